// Round 3
// baseline (224.643 us; speedup 1.0000x reference)
//
#include <hip/hip_runtime.h>
#include <hip/hip_bf16.h>

#define BATCH 8
#define CH    64
#define CH2   32
#define NN    4096
#define BN    (BATCH * NN)   // 32768 rows total

typedef __attribute__((ext_vector_type(8))) short  short8;   // 8 bf16 (MFMA A/B frag)
typedef __attribute__((ext_vector_type(4))) float  floatx4;  // MFMA C/D frag
typedef unsigned short ushort_t;

#define LOG2E 1.4426950408889634f

__device__ __forceinline__ unsigned short f2bf_rne(float f) {
    unsigned int u = __float_as_uint(f);
    return (unsigned short)((u + 0x7FFFu + ((u >> 16) & 1u)) >> 16);
}
// round-half-up: 2 VALU ops, fine for P in [0,1]
__device__ __forceinline__ unsigned short f2bf_fast(float f) {
    unsigned int u = __float_as_uint(f);
    return (unsigned short)((u + 0x8000u) >> 16);
}

// ---- prep 1: x [B][C][N] fp32 -> xT [B*N][64] bf16, plus mlog[row] = 12*||x_row||*log2(e)
__global__ __launch_bounds__(256) void prep_xt(const float* __restrict__ x,
                                               ushort_t* __restrict__ xT,
                                               float* __restrict__ mlog) {
    int g   = blockIdx.x * 256 + threadIdx.x;
    int row = g >> 2;
    int q4  = g & 3;
    int b = row >> 12, n = row & (NN - 1);
    const float* xp = x + (size_t)b * CH * NN + n;
    float ns = 0.f;
    short8 v0, v1;
    #pragma unroll
    for (int j = 0; j < 8; ++j) {
        float a = xp[(size_t)(q4 * 16 + j) * NN];
        ns += a * a;
        v0[j] = (short)f2bf_rne(a);
    }
    #pragma unroll
    for (int j = 0; j < 8; ++j) {
        float a = xp[(size_t)(q4 * 16 + 8 + j) * NN];
        ns += a * a;
        v1[j] = (short)f2bf_rne(a);
    }
    *(short8*)(xT + (size_t)row * CH + q4 * 16)     = v0;
    *(short8*)(xT + (size_t)row * CH + q4 * 16 + 8) = v1;
    ns += __shfl_xor(ns, 1);
    ns += __shfl_xor(ns, 2);
    if (q4 == 0) mlog[row] = 12.0f * sqrtf(ns) * LOG2E;
}

// ---- prep 2 (MFMA): g_x = g_w @ x + g_b -> gxT [B][32 och][N] bf16 (V^T layout)
// 2048 column-tiles of 16; 1 tile per wave; 512 blocks x 4 waves.
__global__ __launch_bounds__(256) void prep_gx(const ushort_t* __restrict__ xT,
                                               const float* __restrict__ gw,
                                               const float* __restrict__ gb,
                                               ushort_t* __restrict__ gxT) {
    int tid = threadIdx.x, wave = tid >> 6, lane = tid & 63;
    int ql = lane & 15, quad = lane >> 4;
    int ti = blockIdx.x * 4 + wave;
    int b = ti >> 8, n0 = (ti & 255) * 16;

    // A = gw rows (och), cast fp32 -> bf16
    short8 af[2][2];
    #pragma unroll
    for (int h = 0; h < 2; ++h)
        #pragma unroll
        for (int ss = 0; ss < 2; ++ss) {
            const float* gp = gw + (h * 16 + ql) * CH + ss * 32 + quad * 8;
            short8 v;
            #pragma unroll
            for (int j = 0; j < 8; ++j) v[j] = (short)f2bf_rne(gp[j]);
            af[h][ss] = v;
        }
    floatx4 acc[2];
    #pragma unroll
    for (int h = 0; h < 2; ++h)
        #pragma unroll
        for (int r = 0; r < 4; ++r) acc[h][r] = gb[h * 16 + quad * 4 + r];

    // B = xT columns (n), contiguous bf16
    const ushort_t* bp = xT + ((size_t)(b * NN + n0 + ql)) * CH + quad * 8;
    short8 b0 = *(const short8*)bp;
    short8 b1 = *(const short8*)(bp + 32);
    #pragma unroll
    for (int h = 0; h < 2; ++h) {
        acc[h] = __builtin_amdgcn_mfma_f32_16x16x32_bf16(af[h][0], b0, acc[h], 0, 0, 0);
        acc[h] = __builtin_amdgcn_mfma_f32_16x16x32_bf16(af[h][1], b1, acc[h], 0, 0, 0);
    }
    #pragma unroll
    for (int h = 0; h < 2; ++h)
        #pragma unroll
        for (int r = 0; r < 4; ++r)
            gxT[((size_t)(b * CH2 + h * 16 + quad * 4 + r)) * NN + n0 + ql] =
                f2bf_rne(acc[h][r]);
}

// ---- flash attention, barrier-free: K/V frags straight from global (L1/L2-resident),
// LDS only for the per-wave P roundtrip. Wave owns 32 query rows (2 row-groups).
// grid = 256 * split blocks, 256 threads (4 waves).
__global__ __launch_bounds__(256, 4) void flash_attn(const ushort_t* __restrict__ xT,
                                                     const ushort_t* __restrict__ gxT,
                                                     const float* __restrict__ mlog,
                                                     float* __restrict__ py,
                                                     float* __restrict__ pl,
                                                     int ksplit) {
    __shared__ ushort_t Plds[4][32 * 72];   // per-wave P [32 rows][64 keys], stride 72

    const int tid = threadIdx.x, wave = tid >> 6, lane = tid & 63;
    const int ql = lane & 15, quad = lane >> 4;
    const int bq = blockIdx.x & 255;        // 256 = 8 batches * 32 qtiles
    const int sp = blockIdx.x >> 8;
    const int b = bq >> 5, qt = bq & 31;
    const int n0 = qt * 128 + wave * 32;
    const int k0 = sp * ksplit;

    short8 qf[2][2];
    float mlr[2][4];
    #pragma unroll
    for (int rg = 0; rg < 2; ++rg) {
        const ushort_t* qp = xT + ((size_t)(b * NN + n0 + rg * 16 + ql)) * CH + quad * 8;
        qf[rg][0] = *(const short8*)qp;
        qf[rg][1] = *(const short8*)(qp + 32);
        float4 m4 = *(const float4*)(mlog + (size_t)b * NN + n0 + rg * 16 + quad * 4);
        mlr[rg][0] = m4.x; mlr[rg][1] = m4.y; mlr[rg][2] = m4.z; mlr[rg][3] = m4.w;
    }

    floatx4 yf[2][2];
    float rs[2][4];
    #pragma unroll
    for (int rg = 0; rg < 2; ++rg) {
        yf[rg][0] = (floatx4){0.f, 0.f, 0.f, 0.f};
        yf[rg][1] = (floatx4){0.f, 0.f, 0.f, 0.f};
        #pragma unroll
        for (int r = 0; r < 4; ++r) rs[rg][r] = 0.f;
    }

    const ushort_t* kb = xT + (size_t)(b * NN + k0) * CH;
    const ushort_t* vb = gxT + (size_t)b * CH2 * NN + k0;
    ushort_t* Pw = Plds[wave];
    const int iters = ksplit >> 6;

    // preload V frags for tile 0
    short8 vf[2][2];
    #pragma unroll
    for (int ss = 0; ss < 2; ++ss)
        #pragma unroll
        for (int h = 0; h < 2; ++h)
            vf[ss][h] = *(const short8*)(vb + (size_t)(h * 16 + ql) * NN + ss * 32 + quad * 8);

    for (int kt = 0; kt < iters; ++kt) {
        // prefetch next tile's V frags
        int ktn = (kt + 1 < iters) ? kt + 1 : kt;
        short8 vfn[2][2];
        #pragma unroll
        for (int ss = 0; ss < 2; ++ss)
            #pragma unroll
            for (int h = 0; h < 2; ++h)
                vfn[ss][h] = *(const short8*)(vb + (size_t)(h * 16 + ql) * NN +
                                              ktn * 64 + ss * 32 + quad * 8);

        const ushort_t* ktb = kb + ((size_t)kt << 12);   // 64 keys * 64 ch

        // QK^T + exp, per 16-key column tile; K frags shared across both row-groups
        #pragma unroll
        for (int ct = 0; ct < 4; ++ct) {
            const ushort_t* kp = ktb + (size_t)(ct * 16 + ql) * CH + quad * 8;
            short8 kf0 = *(const short8*)kp;
            short8 kf1 = *(const short8*)(kp + 32);
            #pragma unroll
            for (int rg = 0; rg < 2; ++rg) {
                floatx4 s = (floatx4){0.f, 0.f, 0.f, 0.f};
                s = __builtin_amdgcn_mfma_f32_16x16x32_bf16(qf[rg][0], kf0, s, 0, 0, 0);
                s = __builtin_amdgcn_mfma_f32_16x16x32_bf16(qf[rg][1], kf1, s, 0, 0, 0);
                #pragma unroll
                for (int r = 0; r < 4; ++r) {
                    float p = exp2f(fmaf(s[r], LOG2E, -mlr[rg][r]));
                    rs[rg][r] += p;
                    Pw[(rg * 16 + quad * 4 + r) * 72 + ct * 16 + ql] = f2bf_fast(p);
                }
            }
        }

        // PV: y[rg][16 rows][32 och] += P[16][64] * V[64][32]
        #pragma unroll
        for (int rg = 0; rg < 2; ++rg)
            #pragma unroll
            for (int ss = 0; ss < 2; ++ss) {
                short8 pf = *(const short8*)(Pw + (rg * 16 + ql) * 72 + ss * 32 + quad * 8);
                #pragma unroll
                for (int h = 0; h < 2; ++h)
                    yf[rg][h] = __builtin_amdgcn_mfma_f32_16x16x32_bf16(pf, vf[ss][h],
                                                                        yf[rg][h], 0, 0, 0);
            }

        #pragma unroll
        for (int ss = 0; ss < 2; ++ss)
            #pragma unroll
            for (int h = 0; h < 2; ++h) vf[ss][h] = vfn[ss][h];
    }

    // epilogue: reduce l across the 16 key-lanes, write partials
    #pragma unroll
    for (int rg = 0; rg < 2; ++rg)
        #pragma unroll
        for (int r = 0; r < 4; ++r) {
            rs[rg][r] += __shfl_xor(rs[rg][r], 1);
            rs[rg][r] += __shfl_xor(rs[rg][r], 2);
            rs[rg][r] += __shfl_xor(rs[rg][r], 4);
            rs[rg][r] += __shfl_xor(rs[rg][r], 8);
        }
    #pragma unroll
    for (int rg = 0; rg < 2; ++rg) {
        size_t rowg = (size_t)b * NN + n0 + rg * 16 + quad * 4;
        #pragma unroll
        for (int r = 0; r < 4; ++r) {
            #pragma unroll
            for (int h = 0; h < 2; ++h)
                py[((size_t)sp * BN + rowg + r) * CH2 + h * 16 + ql] = yf[rg][h][r];
            if (ql == 0) pl[(size_t)sp * BN + rowg + r] = rs[rg][r];
        }
    }
}

// ---- reduction over splits + normalize + output projection + bias + residual
// 1 thread per row; 256 blocks x 128 threads.
__global__ __launch_bounds__(128) void reduce_proj(const float* __restrict__ py,
                                                   const float* __restrict__ pl,
                                                   const float* __restrict__ Ww,
                                                   const float* __restrict__ Wb,
                                                   const float* __restrict__ x,
                                                   float* __restrict__ out,
                                                   int nsplit) {
    __shared__ float WwL[CH * 33];
    __shared__ float WbL[CH];
    int t = threadIdx.x;
    for (int i = t; i < CH * CH2; i += 128) WwL[(i >> 5) * 33 + (i & 31)] = Ww[i];
    if (t < CH) WbL[t] = Wb[t];
    __syncthreads();
    int ng = blockIdx.x * 128 + t;          // global row
    int b = ng >> 12, n = ng & (NN - 1);
    float y[CH2];
    #pragma unroll
    for (int o = 0; o < CH2; ++o) y[o] = 0.f;
    float l = 0.f;
    for (int s = 0; s < nsplit; ++s) {
        l += pl[(size_t)s * BN + ng];
        const float4* yp = (const float4*)(py + ((size_t)s * BN + ng) * CH2);
        #pragma unroll
        for (int o4 = 0; o4 < 8; ++o4) {
            float4 v = yp[o4];
            y[o4 * 4 + 0] += v.x; y[o4 * 4 + 1] += v.y;
            y[o4 * 4 + 2] += v.z; y[o4 * 4 + 3] += v.w;
        }
    }
    float inv = 1.0f / l;
    #pragma unroll
    for (int o = 0; o < CH2; ++o) y[o] *= inv;
    #pragma unroll
    for (int c = 0; c < CH; ++c) {
        float acc = WbL[c];
        #pragma unroll
        for (int o = 0; o < CH2; ++o) acc = fmaf(WwL[c * 33 + o], y[o], acc);
        size_t oi = ((size_t)b * CH + c) * NN + n;
        out[oi] = acc + x[oi];
    }
}

extern "C" void kernel_launch(void* const* d_in, const int* in_sizes, int n_in,
                              void* d_out, int out_size, void* d_ws, size_t ws_size,
                              hipStream_t stream) {
    const float* x  = (const float*)d_in[0];
    const float* gw = (const float*)d_in[1];
    const float* gb = (const float*)d_in[2];
    const float* Ww = (const float*)d_in[3];
    const float* Wb = (const float*)d_in[4];
    float* out = (float*)d_out;

    // workspace layout
    ushort_t* xT   = (ushort_t*)d_ws;                          // BN*64 bf16   = 4 MB
    ushort_t* gxT  = xT + (size_t)BN * CH;                     // B*32*N bf16  = 2 MB
    float*    mlog = (float*)(gxT + (size_t)BATCH * CH2 * NN); // BN fp32      = 128 KB
    float*    py   = mlog + BN;                                // split*BN*32 fp32
    size_t base_bytes = (size_t)BN * CH * 2 + (size_t)BATCH * CH2 * NN * 2 + (size_t)BN * 4;
    int split = 8;
    while (split > 1 && base_bytes + (size_t)split * BN * (CH2 + 1) * 4 > ws_size)
        split >>= 1;
    float* pl = py + (size_t)split * BN * CH2;

    hipLaunchKernelGGL(prep_xt,     dim3(BN * 4 / 256), dim3(256), 0, stream, x, xT, mlog);
    hipLaunchKernelGGL(prep_gx,     dim3(BN / 16 / 4),  dim3(256), 0, stream, xT, gw, gb, gxT);
    hipLaunchKernelGGL(flash_attn,  dim3(256 * split),  dim3(256), 0, stream,
                       xT, gxT, mlog, py, pl, NN / split);
    hipLaunchKernelGGL(reduce_proj, dim3(BN / 128),     dim3(128), 0, stream,
                       py, pl, Ww, Wb, x, out, split);
}

// Round 4
// 167.906 us; speedup vs baseline: 1.3379x; 1.3379x over previous
//
#include <hip/hip_runtime.h>
#include <hip/hip_bf16.h>

#define BATCH 8
#define CH    64
#define CH2   32
#define NN    4096
#define BN    (BATCH * NN)   // 32768 rows total

typedef __attribute__((ext_vector_type(8))) short  short8;   // 8 bf16 (MFMA A/B frag)
typedef __attribute__((ext_vector_type(4))) float  floatx4;  // MFMA C/D frag
typedef unsigned short ushort_t;

#define LOG2E 1.4426950408889634f

__device__ __forceinline__ unsigned short f2bf_rne(float f) {
    unsigned int u = __float_as_uint(f);
    return (unsigned short)((u + 0x7FFFu + ((u >> 16) & 1u)) >> 16);
}
// round-half-up: 2 VALU ops, fine for P in (0,1]
__device__ __forceinline__ unsigned short f2bf_fast(float f) {
    unsigned int u = __float_as_uint(f);
    return (unsigned short)((u + 0x8000u) >> 16);
}

// ---- prep 1: x [B][C][N] fp32 -> xT [B*N][64] bf16, plus mlog[row] = 12*||x_row||*log2(e)
__global__ __launch_bounds__(256) void prep_xt(const float* __restrict__ x,
                                               ushort_t* __restrict__ xT,
                                               float* __restrict__ mlog) {
    int g   = blockIdx.x * 256 + threadIdx.x;
    int row = g >> 2;
    int q4  = g & 3;
    int b = row >> 12, n = row & (NN - 1);
    const float* xp = x + (size_t)b * CH * NN + n;
    float ns = 0.f;
    short8 v0, v1;
    #pragma unroll
    for (int j = 0; j < 8; ++j) {
        float a = xp[(size_t)(q4 * 16 + j) * NN];
        ns += a * a;
        v0[j] = (short)f2bf_rne(a);
    }
    #pragma unroll
    for (int j = 0; j < 8; ++j) {
        float a = xp[(size_t)(q4 * 16 + 8 + j) * NN];
        ns += a * a;
        v1[j] = (short)f2bf_rne(a);
    }
    *(short8*)(xT + (size_t)row * CH + q4 * 16)     = v0;
    *(short8*)(xT + (size_t)row * CH + q4 * 16 + 8) = v1;
    ns += __shfl_xor(ns, 1);
    ns += __shfl_xor(ns, 2);
    if (q4 == 0) mlog[row] = 12.0f * sqrtf(ns) * LOG2E;
}

// ---- prep 2 (MFMA): g_x = g_w @ x + g_b -> gxT [B][32 och][N] bf16 (V^T layout)
__global__ __launch_bounds__(256) void prep_gx(const ushort_t* __restrict__ xT,
                                               const float* __restrict__ gw,
                                               const float* __restrict__ gb,
                                               ushort_t* __restrict__ gxT) {
    int tid = threadIdx.x, wave = tid >> 6, lane = tid & 63;
    int ql = lane & 15, quad = lane >> 4;
    int ti = blockIdx.x * 4 + wave;
    int b = ti >> 8, n0 = (ti & 255) * 16;

    short8 af[2][2];
    #pragma unroll
    for (int h = 0; h < 2; ++h)
        #pragma unroll
        for (int ss = 0; ss < 2; ++ss) {
            const float* gp = gw + (h * 16 + ql) * CH + ss * 32 + quad * 8;
            short8 v;
            #pragma unroll
            for (int j = 0; j < 8; ++j) v[j] = (short)f2bf_rne(gp[j]);
            af[h][ss] = v;
        }
    floatx4 acc[2];
    #pragma unroll
    for (int h = 0; h < 2; ++h)
        #pragma unroll
        for (int r = 0; r < 4; ++r) acc[h][r] = gb[h * 16 + quad * 4 + r];

    const ushort_t* bp = xT + ((size_t)(b * NN + n0 + ql)) * CH + quad * 8;
    short8 b0 = *(const short8*)bp;
    short8 b1 = *(const short8*)(bp + 32);
    #pragma unroll
    for (int h = 0; h < 2; ++h) {
        acc[h] = __builtin_amdgcn_mfma_f32_16x16x32_bf16(af[h][0], b0, acc[h], 0, 0, 0);
        acc[h] = __builtin_amdgcn_mfma_f32_16x16x32_bf16(af[h][1], b1, acc[h], 0, 0, 0);
    }
    #pragma unroll
    for (int h = 0; h < 2; ++h)
        #pragma unroll
        for (int r = 0; r < 4; ++r)
            gxT[((size_t)(b * CH2 + h * 16 + quad * 4 + r)) * NN + n0 + ql] =
                f2bf_rne(acc[h][r]);
}

// ---- flash attention: LDS double-buffered K tile (1 barrier/iter), V frags from
// global with register prefetch, 32 q-rows/wave, fixed per-row softmax shift.
// grid = 256 * split blocks (128 q-rows per block), 256 threads (4 waves).
__global__ __launch_bounds__(256, 4) void flash_attn(const ushort_t* __restrict__ xT,
                                                     const ushort_t* __restrict__ gxT,
                                                     const float* __restrict__ mlog,
                                                     float* __restrict__ py,
                                                     float* __restrict__ pl,
                                                     int ksplit) {
    __shared__ ushort_t Kd[2][64 * 72];     // ping-pong key tile [key][ch], stride 72
    __shared__ ushort_t Plds[4][32 * 72];   // per-wave P [row][key], stride 72

    const int tid = threadIdx.x, wave = tid >> 6, lane = tid & 63;
    const int ql = lane & 15, quad = lane >> 4;
    const int bq = blockIdx.x & 255;        // 256 = 8 batches * 32 qtiles(128)
    const int sp = blockIdx.x >> 8;
    const int b = bq >> 5, qt = bq & 31;
    const int n0 = qt * 128 + wave * 32;
    const int k0 = sp * ksplit;

    short8 qf[2][2];
    float mlr[2][4];
    #pragma unroll
    for (int rg = 0; rg < 2; ++rg) {
        const ushort_t* qp = xT + ((size_t)(b * NN + n0 + rg * 16 + ql)) * CH + quad * 8;
        qf[rg][0] = *(const short8*)qp;
        qf[rg][1] = *(const short8*)(qp + 32);
        float4 m4 = *(const float4*)(mlog + (size_t)b * NN + n0 + rg * 16 + quad * 4);
        mlr[rg][0] = m4.x; mlr[rg][1] = m4.y; mlr[rg][2] = m4.z; mlr[rg][3] = m4.w;
    }

    floatx4 yf[2][2];
    float rs[2][4];
    #pragma unroll
    for (int rg = 0; rg < 2; ++rg) {
        yf[rg][0] = (floatx4){0.f, 0.f, 0.f, 0.f};
        yf[rg][1] = (floatx4){0.f, 0.f, 0.f, 0.f};
        #pragma unroll
        for (int r = 0; r < 4; ++r) rs[rg][r] = 0.f;
    }

    const ushort_t* kb = xT + (size_t)(b * NN + k0) * CH;
    const ushort_t* vb = gxT + (size_t)b * CH2 * NN + k0;
    ushort_t* Pw = Plds[wave];
    const int iters = ksplit >> 6;

    const int skey = tid >> 3;              // staging: thread covers (key, c0) and (key+32, c0)
    const int sc0  = (tid & 7) * 8;

    // stage tile 0, preload V frags tile 0
    #pragma unroll
    for (int i = 0; i < 2; ++i)
        *(short8*)(&Kd[0][(skey + i * 32) * 72 + sc0]) =
            *(const short8*)(kb + (size_t)(skey + i * 32) * CH + sc0);
    short8 vf[2][2];
    #pragma unroll
    for (int ss = 0; ss < 2; ++ss)
        #pragma unroll
        for (int h = 0; h < 2; ++h)
            vf[ss][h] = *(const short8*)(vb + (size_t)(h * 16 + ql) * NN + ss * 32 + quad * 8);
    __syncthreads();

    for (int kt = 0; kt < iters; ++kt) {
        const int pp = kt & 1;
        // issue next tile's global loads early (regs) — overlap with compute below
        short8 kvn[2];
        if (kt + 1 < iters) {
            #pragma unroll
            for (int i = 0; i < 2; ++i)
                kvn[i] = *(const short8*)(kb + ((size_t)(kt + 1) << 12) +
                                          (size_t)(skey + i * 32) * CH + sc0);
        }
        short8 vfn[2][2];
        {
            int ktn = (kt + 1 < iters) ? kt + 1 : kt;
            #pragma unroll
            for (int ss = 0; ss < 2; ++ss)
                #pragma unroll
                for (int h = 0; h < 2; ++h)
                    vfn[ss][h] = *(const short8*)(vb + (size_t)(h * 16 + ql) * NN +
                                                  ktn * 64 + ss * 32 + quad * 8);
        }

        // QK^T + exp: K frags from LDS, shared across both row-groups
        const ushort_t* Kp = Kd[pp];
        #pragma unroll
        for (int ct = 0; ct < 4; ++ct) {
            short8 kf0 = *(const short8*)(Kp + (ct * 16 + ql) * 72 + quad * 8);
            short8 kf1 = *(const short8*)(Kp + (ct * 16 + ql) * 72 + 32 + quad * 8);
            #pragma unroll
            for (int rg = 0; rg < 2; ++rg) {
                floatx4 s = (floatx4){0.f, 0.f, 0.f, 0.f};
                s = __builtin_amdgcn_mfma_f32_16x16x32_bf16(qf[rg][0], kf0, s, 0, 0, 0);
                s = __builtin_amdgcn_mfma_f32_16x16x32_bf16(qf[rg][1], kf1, s, 0, 0, 0);
                #pragma unroll
                for (int r = 0; r < 4; ++r) {
                    float p = exp2f(fmaf(s[r], LOG2E, -mlr[rg][r]));
                    rs[rg][r] += p;
                    Pw[(rg * 16 + quad * 4 + r) * 72 + ct * 16 + ql] = f2bf_fast(p);
                }
            }
        }

        // PV: y[rg][16 rows][32 och] += P[16][64] * V[64][32]
        #pragma unroll
        for (int rg = 0; rg < 2; ++rg)
            #pragma unroll
            for (int ss = 0; ss < 2; ++ss) {
                short8 pf = *(const short8*)(Pw + (rg * 16 + ql) * 72 + ss * 32 + quad * 8);
                #pragma unroll
                for (int h = 0; h < 2; ++h)
                    yf[rg][h] = __builtin_amdgcn_mfma_f32_16x16x32_bf16(pf, vf[ss][h],
                                                                        yf[rg][h], 0, 0, 0);
            }

        // stage next tile into the other buffer (safe: end-of-previous-iter barrier)
        if (kt + 1 < iters) {
            #pragma unroll
            for (int i = 0; i < 2; ++i)
                *(short8*)(&Kd[1 - pp][(skey + i * 32) * 72 + sc0]) = kvn[i];
        }
        __syncthreads();
        #pragma unroll
        for (int ss = 0; ss < 2; ++ss)
            #pragma unroll
            for (int h = 0; h < 2; ++h) vf[ss][h] = vfn[ss][h];
    }

    // epilogue: reduce l across the 16 key-lanes, write partials
    #pragma unroll
    for (int rg = 0; rg < 2; ++rg)
        #pragma unroll
        for (int r = 0; r < 4; ++r) {
            rs[rg][r] += __shfl_xor(rs[rg][r], 1);
            rs[rg][r] += __shfl_xor(rs[rg][r], 2);
            rs[rg][r] += __shfl_xor(rs[rg][r], 4);
            rs[rg][r] += __shfl_xor(rs[rg][r], 8);
        }
    #pragma unroll
    for (int rg = 0; rg < 2; ++rg) {
        size_t rowg = (size_t)b * NN + n0 + rg * 16 + quad * 4;
        #pragma unroll
        for (int r = 0; r < 4; ++r) {
            #pragma unroll
            for (int h = 0; h < 2; ++h)
                py[((size_t)sp * BN + rowg + r) * CH2 + h * 16 + ql] = yf[rg][h][r];
            if (ql == 0) pl[(size_t)sp * BN + rowg + r] = rs[rg][r];
        }
    }
}

// ---- reduction over splits + normalize + output projection + bias + residual
// Fully coalesced: block handles 256 consecutive rows; py streamed as contiguous
// float4s; per-row scaling + projection via padded LDS tiles.
__global__ __launch_bounds__(256) void reduce_proj(const float* __restrict__ py,
                                                   const float* __restrict__ pl,
                                                   const float* __restrict__ Ww,
                                                   const float* __restrict__ Wb,
                                                   const float* __restrict__ x,
                                                   float* __restrict__ out,
                                                   int nsplit) {
    __shared__ float WwL[CH * 33];
    __shared__ float WbL[CH];
    __shared__ float linv[256];
    __shared__ float Y[256 * 33];           // [row][och], +1 pad
    int t = threadIdx.x;
    for (int i = t; i < CH * CH2; i += 256) WwL[(i >> 5) * 33 + (i & 31)] = Ww[i];
    if (t < CH) WbL[t] = Wb[t];

    int row0 = blockIdx.x * 256;
    float4 acc4[8];
    #pragma unroll
    for (int c = 0; c < 8; ++c) acc4[c] = (float4){0.f, 0.f, 0.f, 0.f};
    float l = 0.f;
    for (int s = 0; s < nsplit; ++s) {
        l += pl[(size_t)s * BN + row0 + t];
        const float4* p4 = (const float4*)(py + ((size_t)s * BN + row0) * CH2);
        #pragma unroll
        for (int c = 0; c < 8; ++c) {
            float4 v = p4[c * 256 + t];     // fully coalesced 4 KB per instruction
            acc4[c].x += v.x; acc4[c].y += v.y; acc4[c].z += v.z; acc4[c].w += v.w;
        }
    }
    linv[t] = 1.0f / l;
    __syncthreads();
    #pragma unroll
    for (int c = 0; c < 8; ++c) {
        int f = c * 256 + t;
        int r = f >> 3, o = f & 7;          // row within block, float4 slot
        float sc = linv[r];
        Y[r * 33 + o * 4 + 0] = acc4[c].x * sc;
        Y[r * 33 + o * 4 + 1] = acc4[c].y * sc;
        Y[r * 33 + o * 4 + 2] = acc4[c].z * sc;
        Y[r * 33 + o * 4 + 3] = acc4[c].w * sc;
    }
    __syncthreads();

    float y[CH2];
    #pragma unroll
    for (int o = 0; o < CH2; ++o) y[o] = Y[t * 33 + o];
    int g = row0 + t, b = g >> 12, n = g & (NN - 1);
    #pragma unroll
    for (int c = 0; c < CH; ++c) {
        float acc = WbL[c];
        #pragma unroll
        for (int o = 0; o < CH2; ++o) acc = fmaf(WwL[c * 33 + o], y[o], acc);
        size_t oi = ((size_t)b * CH + c) * NN + n;
        out[oi] = acc + x[oi];              // coalesced: lanes span consecutive n
    }
}

extern "C" void kernel_launch(void* const* d_in, const int* in_sizes, int n_in,
                              void* d_out, int out_size, void* d_ws, size_t ws_size,
                              hipStream_t stream) {
    const float* x  = (const float*)d_in[0];
    const float* gw = (const float*)d_in[1];
    const float* gb = (const float*)d_in[2];
    const float* Ww = (const float*)d_in[3];
    const float* Wb = (const float*)d_in[4];
    float* out = (float*)d_out;

    // workspace layout
    ushort_t* xT   = (ushort_t*)d_ws;                          // BN*64 bf16   = 4 MB
    ushort_t* gxT  = xT + (size_t)BN * CH;                     // B*32*N bf16  = 2 MB
    float*    mlog = (float*)(gxT + (size_t)BATCH * CH2 * NN); // BN fp32      = 128 KB
    float*    py   = mlog + BN;                                // split*BN*32 fp32
    size_t base_bytes = (size_t)BN * CH * 2 + (size_t)BATCH * CH2 * NN * 2 + (size_t)BN * 4;
    int split = 4;
    while (split > 1 && base_bytes + (size_t)split * BN * (CH2 + 1) * 4 > ws_size)
        split >>= 1;
    float* pl = py + (size_t)split * BN * CH2;

    hipLaunchKernelGGL(prep_xt,     dim3(BN * 4 / 256), dim3(256), 0, stream, x, xT, mlog);
    hipLaunchKernelGGL(prep_gx,     dim3(BN / 16 / 4),  dim3(256), 0, stream, xT, gw, gb, gxT);
    hipLaunchKernelGGL(flash_attn,  dim3(256 * split),  dim3(256), 0, stream,
                       xT, gxT, mlog, py, pl, NN / split);
    hipLaunchKernelGGL(reduce_proj, dim3(BN / 256),     dim3(256), 0, stream,
                       py, pl, Ww, Wb, x, out, split);
}